// Round 6
// baseline (1864.278 us; speedup 1.0000x reference)
//
#include <hip/hip_runtime.h>
#include <math.h>

#define N_ATOMS 50000
#define N_EDGES 1600000
#define NF 128
#define NG 50
#define ITERS 8
#define EPB 512            // 4 waves x 16 edges x 8 iters
#define LOG2F_ 0.69314718055994530942f
#define PI_OVER_CUT 0.31415926535897932f
#define CUTOFF_F 10.0f

typedef _Float16 half_t;
typedef _Float16 f16x8 __attribute__((ext_vector_type(8)));
typedef _Float16 f16x2 __attribute__((ext_vector_type(2)));
typedef float f32x4 __attribute__((ext_vector_type(4)));

__device__ __forceinline__ float sspf_fast(float x) {
    float e = __expf(-fabsf(x));
    float l = __logf(1.0f + e);
    return fmaxf(x, 0.0f) + (l - LOG2F_);
}

__device__ __forceinline__ unsigned short f2h_bits(float x) {
    half_t h = (half_t)x;
    return __builtin_bit_cast(unsigned short, h);
}

// ---------------- fp32 node GEMM (unchanged) ----------------
template <bool BIAS_SSP>
__global__ __launch_bounds__(256) void gemm128_kernel(
    const float* __restrict__ X, const float* __restrict__ W,
    const float* __restrict__ bias, float* __restrict__ Y, int N) {
    __shared__ float xs[32][128];
    const int row0 = blockIdx.x * 32;
    const int tid = threadIdx.x;
    {
        const float4* src = (const float4*)(X + (size_t)row0 * 128);
        float4* dst = (float4*)(&xs[0][0]);
        for (int i = tid; i < 32 * 32; i += 256) {
            int r = i >> 5;
            float4 v = {0.f, 0.f, 0.f, 0.f};
            if (row0 + r < N) v = src[i];
            dst[i] = v;
        }
    }
    __syncthreads();

    const int rq = tid >> 5;
    const int cq = tid & 31;
    float4 a0 = {0,0,0,0}, a1 = {0,0,0,0}, a2 = {0,0,0,0}, a3 = {0,0,0,0};
    const float4* Wv = (const float4*)W;

    #pragma unroll 4
    for (int k = 0; k < 128; ++k) {
        float4 w = Wv[k * 32 + cq];
        float x0 = xs[rq * 4 + 0][k];
        float x1 = xs[rq * 4 + 1][k];
        float x2 = xs[rq * 4 + 2][k];
        float x3 = xs[rq * 4 + 3][k];
        a0.x += x0 * w.x; a0.y += x0 * w.y; a0.z += x0 * w.z; a0.w += x0 * w.w;
        a1.x += x1 * w.x; a1.y += x1 * w.y; a1.z += x1 * w.z; a1.w += x1 * w.w;
        a2.x += x2 * w.x; a2.y += x2 * w.y; a2.z += x2 * w.z; a2.w += x2 * w.w;
        a3.x += x3 * w.x; a3.y += x3 * w.y; a3.z += x3 * w.z; a3.w += x3 * w.w;
    }

    float4 bq = {0,0,0,0};
    if (BIAS_SSP) bq = ((const float4*)bias)[cq];
    #pragma unroll
    for (int i = 0; i < 4; ++i) {
        float4 v = (i == 0) ? a0 : (i == 1) ? a1 : (i == 2) ? a2 : a3;
        int r = row0 + rq * 4 + i;
        if (r >= N) continue;
        if (BIAS_SSP) {
            v.x = sspf_fast(v.x + bq.x); v.y = sspf_fast(v.y + bq.y);
            v.z = sspf_fast(v.z + bq.z); v.w = sspf_fast(v.w + bq.w);
        }
        ((float4*)(Y + (size_t)r * 128))[cq] = v;
    }
}

// ---------------- weight pre-convert: f32 -> f16, transposed ----------------
__global__ __launch_bounds__(256) void preconv_kernel(
    const float* __restrict__ Wf1, const float* __restrict__ Wf2,
    half_t* __restrict__ w1t, half_t* __restrict__ w2t) {
    int id = blockIdx.x * 256 + threadIdx.x;
    if (id < 128 * 64) {
        int col = id >> 6, k = id & 63;
        w1t[id] = (k < NG) ? (half_t)Wf1[k * NF + col] : (half_t)0.0f;
    } else if (id < 128 * 64 + 128 * 128) {
        int t = id - 128 * 64;
        int col = t >> 7, k = t & 127;
        w2t[t] = (half_t)Wf2[k * NF + col];
    }
}

// LDS: only per-wave W1OUT [16][128] f16 swizzled, 4 KB/wave x 4 waves
__global__ __launch_bounds__(256, 8) void edge_kernel(
    const float* __restrict__ f_ij, const float* __restrict__ r_ij,
    const int* __restrict__ ind_i, const int* __restrict__ ind_j,
    const half_t* __restrict__ w1t_g, const half_t* __restrict__ w2t_g,
    const float* __restrict__ bf1, const float* __restrict__ bf2,
    const float* __restrict__ h, float* __restrict__ agg) {
    __shared__ __align__(16) unsigned char lds[16384];
    const int tid = threadIdx.x;

    const int lane = tid & 63;
    const int wid = tid >> 6;          // 0..3
    const int l15 = lane & 15;
    const int lg  = lane >> 4;
    const int l7  = lane & 7;
    const int h3  = l15 >> 3;
    const int hb  = (l7 >> 2) & 1;
    const int lgl = lg ^ (l7 & 3);

    float b1r[8], b2r[8];
    #pragma unroll
    for (int t = 0; t < 8; ++t) {
        b1r[t] = bf1[t * 16 + l15];
        b2r[t] = bf2[t * 16 + l15];
    }

    // B operand pointers (natural [col][k] f16 layout, L2-resident)
    const half_t* w1p = w1t_g + l15 * 64 + lg * 8;    // + t*1024 + ks*32
    const half_t* w2p = w2t_g + l15 * 128 + lg * 8;   // + t*2048 + ks*32

    // per-wave W1OUT swizzled LDS (write in epilogue1, read as GEMM2 A)
    const int a2b0 = wid * 4096 + (l15 << 8) + (hb << 6) + (lgl << 4);
    const int a2b1 = wid * 4096 + (l15 << 8) + ((hb ^ 1) << 6) + (lgl << 4);
    const int ep1base = wid * 4096 + lg * 1024 + l7 * 2;
    const int rw4 = (lg & 1) * 4;

    const int bb = blockIdx.x * EPB;
    const float* aptr = f_ij + (size_t)(bb + wid * 16 + l15) * NG + lg * 8;

    for (int it = 0; it < ITERS; ++it) {
        const int eb = bb + it * 64 + wid * 16;

        // ---- A fragments: global -> registers ----
        float2 q[8];
        #pragma unroll
        for (int p = 0; p < 4; ++p) q[p] = *(const float2*)(aptr + 2 * p);
        #pragma unroll
        for (int p = 0; p < 4; ++p) {
            float2 v = {0.f, 0.f};
            if (lg * 8 + 2 * p <= 16) v = *(const float2*)(aptr + 32 + 2 * p);
            q[4 + p] = v;
        }
        f16x8 a1[2];
        #pragma unroll
        for (int ks = 0; ks < 2; ++ks) {
            #pragma unroll
            for (int p = 0; p < 4; ++p) {
                f16x2 hv = __builtin_bit_cast(f16x2,
                    __builtin_amdgcn_cvt_pkrtz(q[ks * 4 + p].x, q[ks * 4 + p].y));
                a1[ks][2 * p]     = hv[0];
                a1[ks][2 * p + 1] = hv[1];
            }
        }
        aptr += (size_t)64 * NG;

        // ---- GEMM1: B streamed from L2 ----
        f32x4 acc1[8];
        #pragma unroll
        for (int t = 0; t < 8; ++t) acc1[t] = (f32x4){0.f, 0.f, 0.f, 0.f};
        #pragma unroll
        for (int t = 0; t < 8; ++t) {
            f16x8 b0 = *(const f16x8*)(w1p + t * 1024);
            f16x8 b1 = *(const f16x8*)(w1p + t * 1024 + 32);
            acc1[t] = __builtin_amdgcn_mfma_f32_16x16x32_f16(a1[0], b0, acc1[t], 0, 0, 0);
            acc1[t] = __builtin_amdgcn_mfma_f32_16x16x32_f16(a1[1], b1, acc1[t], 0, 0, 0);
        }

        // ---- epilogue1: ssp -> f16 -> per-wave W1OUT (swizzled LDS) ----
        #pragma unroll
        for (int t = 0; t < 8; ++t) {
            #pragma unroll
            for (int r = 0; r < 4; ++r) {
                unsigned short bits = f2h_bits(sspf_fast(acc1[t][r] + b1r[t]));
                int slotx = (2 * (t & 3) + h3) ^ (rw4 + r);
                *(unsigned short*)(lds + ep1base + r * 256 + ((t >> 2) << 7) + (slotx << 4)) = bits;
            }
        }

        // ---- GEMM2: A from LDS, B streamed from L2 ----
        f32x4 acc2[8];
        #pragma unroll
        for (int t = 0; t < 8; ++t) acc2[t] = (f32x4){0.f, 0.f, 0.f, 0.f};
        f16x8 a2[4];
        #pragma unroll
        for (int ks = 0; ks < 4; ++ks) {
            int addr = ((ks & 1) ? a2b1 : a2b0) + (ks >> 1) * 128;
            a2[ks] = *(const f16x8*)(lds + addr);
        }
        #pragma unroll
        for (int t = 0; t < 8; ++t) {
            #pragma unroll
            for (int ks = 0; ks < 4; ++ks) {
                f16x8 b = *(const f16x8*)(w2p + t * 2048 + ks * 32);
                acc2[t] = __builtin_amdgcn_mfma_f32_16x16x32_f16(a2[ks], b, acc2[t], 0, 0, 0);
            }
        }

        // ---- epilogue2: ssp*cutoff, gather h[j], scatter-add agg[i] ----
        const int erow = eb + lg * 4;
        float rv[4]; int jv[4], iv[4];
        #pragma unroll
        for (int r = 0; r < 4; ++r) {
            rv[r] = r_ij[erow + r];
            jv[r] = ind_j[erow + r];
            iv[r] = ind_i[erow + r];
        }
        #pragma unroll
        for (int r = 0; r < 4; ++r) {
            float c = 0.5f * (__cosf(rv[r] * PI_OVER_CUT) + 1.0f);
            c = (rv[r] < CUTOFF_F) ? c : 0.0f;
            const float* hrow = h + (size_t)jv[r] * NF + l15;
            float* grow = agg + (size_t)iv[r] * NF + l15;
            #pragma unroll
            for (int t = 0; t < 8; ++t) {
                float w2 = sspf_fast(acc2[t][r] + b2r[t]) * c;
                atomicAdd(grow + t * 16, hrow[t * 16] * w2);
            }
        }
    }
}

extern "C" void kernel_launch(void* const* d_in, const int* in_sizes, int n_in,
                              void* d_out, int out_size, void* d_ws, size_t ws_size,
                              hipStream_t stream) {
    const float* x     = (const float*)d_in[0];
    const float* r_ij  = (const float*)d_in[1];
    const float* f_ij  = (const float*)d_in[2];
    const int*   ind_i = (const int*)d_in[3];
    const int*   ind_j = (const int*)d_in[4];
    const float* Wf1   = (const float*)d_in[5];
    const float* bf1   = (const float*)d_in[6];
    const float* Wf2   = (const float*)d_in[7];
    const float* bf2   = (const float*)d_in[8];
    const float* Win   = (const float*)d_in[9];
    const float* Wout  = (const float*)d_in[10];
    const float* bout  = (const float*)d_in[11];
    float* out = (float*)d_out;

    float*  agg  = (float*)d_ws;
    float*  h    = agg + (size_t)N_ATOMS * NF;
    half_t* w1t  = (half_t*)(h + (size_t)N_ATOMS * NF);
    half_t* w2t  = w1t + 128 * 64;

    (void)hipMemsetAsync(agg, 0, (size_t)N_ATOMS * NF * sizeof(float), stream);

    preconv_kernel<<<96, 256, 0, stream>>>(Wf1, Wf2, w1t, w2t);

    const int gemm_blocks = (N_ATOMS + 31) / 32;
    gemm128_kernel<false><<<gemm_blocks, 256, 0, stream>>>(x, Win, nullptr, h, N_ATOMS);

    edge_kernel<<<N_EDGES / EPB, 256, 0, stream>>>(f_ij, r_ij, ind_i, ind_j,
                                                   w1t, w2t, bf1, bf2, h, agg);

    gemm128_kernel<true><<<gemm_blocks, 256, 0, stream>>>(agg, Wout, bout, out, N_ATOMS);
}

// Round 7
// 756.951 us; speedup vs baseline: 2.4629x; 2.4629x over previous
//
#include <hip/hip_runtime.h>
#include <math.h>

#define N_ATOMS 50000
#define N_EDGES 1600000
#define NF 128
#define NG 50
#define ITERS 4
#define EPB 512            // 8 waves x 16 edges x 4 iters
#define LOG2F_ 0.69314718055994530942f
#define PI_OVER_CUT 0.31415926535897932f
#define CUTOFF_F 10.0f

typedef _Float16 half_t;
typedef _Float16 f16x8 __attribute__((ext_vector_type(8)));
typedef _Float16 f16x2 __attribute__((ext_vector_type(2)));
typedef float f32x4 __attribute__((ext_vector_type(4)));
typedef unsigned int u32x4 __attribute__((ext_vector_type(4)));

__device__ __forceinline__ float sspf_fast(float x) {
    float e = __expf(-fabsf(x));
    float l = __logf(1.0f + e);
    return fmaxf(x, 0.0f) + (l - LOG2F_);
}

__device__ __forceinline__ unsigned short f2h_bits(float x) {
    half_t h = (half_t)x;
    return __builtin_bit_cast(unsigned short, h);
}

// ---------------- fp32 node GEMM (unchanged) ----------------
template <bool BIAS_SSP>
__global__ __launch_bounds__(256) void gemm128_kernel(
    const float* __restrict__ X, const float* __restrict__ W,
    const float* __restrict__ bias, float* __restrict__ Y, int N) {
    __shared__ float xs[32][128];
    const int row0 = blockIdx.x * 32;
    const int tid = threadIdx.x;
    {
        const float4* src = (const float4*)(X + (size_t)row0 * 128);
        float4* dst = (float4*)(&xs[0][0]);
        for (int i = tid; i < 32 * 32; i += 256) {
            int r = i >> 5;
            float4 v = {0.f, 0.f, 0.f, 0.f};
            if (row0 + r < N) v = src[i];
            dst[i] = v;
        }
    }
    __syncthreads();

    const int rq = tid >> 5;
    const int cq = tid & 31;
    float4 a0 = {0,0,0,0}, a1 = {0,0,0,0}, a2 = {0,0,0,0}, a3 = {0,0,0,0};
    const float4* Wv = (const float4*)W;

    #pragma unroll 4
    for (int k = 0; k < 128; ++k) {
        float4 w = Wv[k * 32 + cq];
        float x0 = xs[rq * 4 + 0][k];
        float x1 = xs[rq * 4 + 1][k];
        float x2 = xs[rq * 4 + 2][k];
        float x3 = xs[rq * 4 + 3][k];
        a0.x += x0 * w.x; a0.y += x0 * w.y; a0.z += x0 * w.z; a0.w += x0 * w.w;
        a1.x += x1 * w.x; a1.y += x1 * w.y; a1.z += x1 * w.z; a1.w += x1 * w.w;
        a2.x += x2 * w.x; a2.y += x2 * w.y; a2.z += x2 * w.z; a2.w += x2 * w.w;
        a3.x += x3 * w.x; a3.y += x3 * w.y; a3.z += x3 * w.z; a3.w += x3 * w.w;
    }

    float4 bq = {0,0,0,0};
    if (BIAS_SSP) bq = ((const float4*)bias)[cq];
    #pragma unroll
    for (int i = 0; i < 4; ++i) {
        float4 v = (i == 0) ? a0 : (i == 1) ? a1 : (i == 2) ? a2 : a3;
        int r = row0 + rq * 4 + i;
        if (r >= N) continue;
        if (BIAS_SSP) {
            v.x = sspf_fast(v.x + bq.x); v.y = sspf_fast(v.y + bq.y);
            v.z = sspf_fast(v.z + bq.z); v.w = sspf_fast(v.w + bq.w);
        }
        ((float4*)(Y + (size_t)r * 128))[cq] = v;
    }
}

// ---------------- weight pre-convert: f32 -> f16, transposed ----------------
__global__ __launch_bounds__(256) void preconv_kernel(
    const float* __restrict__ Wf1, const float* __restrict__ Wf2,
    half_t* __restrict__ w1t, half_t* __restrict__ w2t) {
    int id = blockIdx.x * 256 + threadIdx.x;
    if (id < 128 * 64) {
        int col = id >> 6, k = id & 63;
        w1t[id] = (k < NG) ? (half_t)Wf1[k * NF + col] : (half_t)0.0f;
    } else if (id < 128 * 64 + 128 * 128) {
        int t = id - 128 * 64;
        int col = t >> 7, k = t & 127;
        w2t[t] = (half_t)Wf2[k * NF + col];
    }
}

// LDS: [0,16384) W1T swz | [16384,49152) W2T swz | [49152,81920) 8x4KB W1OUT
#define OFF_W2T   16384
#define OFF_W1OUT 49152

__global__ __launch_bounds__(512, 4) void edge_kernel(
    const float* __restrict__ f_ij, const float* __restrict__ r_ij,
    const int* __restrict__ ind_i, const int* __restrict__ ind_j,
    const half_t* __restrict__ w1t_g, const half_t* __restrict__ w2t_g,
    const float* __restrict__ bf1, const float* __restrict__ bf2,
    const float* __restrict__ h, float* __restrict__ agg) {
    __shared__ __align__(16) unsigned char lds[81920];
    const int tid = threadIdx.x;

    // ---- stage weights once per block ----
    for (int c = tid; c < 1024; c += 512) {
        int col = c >> 3, kc = c & 7;
        u32x4 v = ((const u32x4*)w1t_g)[c];
        *(u32x4*)(lds + (col << 7) + ((kc ^ (col & 7)) << 4)) = v;
    }
    for (int c = tid; c < 2048; c += 512) {
        int col = c >> 4, kc = c & 15;
        u32x4 v = ((const u32x4*)w2t_g)[c];
        int slot = (kc & 8) | ((kc & 7) ^ (col & 7));
        *(u32x4*)(lds + OFF_W2T + (col << 8) + (slot << 4)) = v;
    }

    const int lane = tid & 63;
    const int wid = tid >> 6;          // 0..7
    const int l15 = lane & 15;
    const int lg  = lane >> 4;
    const int l7  = lane & 7;
    const int h3  = l15 >> 3;
    const int hb  = (l7 >> 2) & 1;
    const int lgl = lg ^ (l7 & 3);

    float b1r[8], b2r[8];
    #pragma unroll
    for (int t = 0; t < 8; ++t) {
        b1r[t] = bf1[t * 16 + l15];
        b2r[t] = bf2[t * 16 + l15];
    }

    const int b1b0 = (l15 << 7) + (hb << 6) + (lgl << 4);
    const int b1b1 = (l15 << 7) + ((hb ^ 1) << 6) + (lgl << 4);
    const int b2b0 = OFF_W2T + (l15 << 8) + (hb << 6) + (lgl << 4);
    const int b2b1 = OFF_W2T + (l15 << 8) + ((hb ^ 1) << 6) + (lgl << 4);
    const int a2b0 = OFF_W1OUT + wid * 4096 + (l15 << 8) + (hb << 6) + (lgl << 4);
    const int a2b1 = OFF_W1OUT + wid * 4096 + (l15 << 8) + ((hb ^ 1) << 6) + (lgl << 4);
    const int ep1base = OFF_W1OUT + wid * 4096 + lg * 1024 + l7 * 2;
    const int rw4 = (lg & 1) * 4;

    const int bb = blockIdx.x * EPB;
    const float* aptr = f_ij + (size_t)(bb + wid * 16 + l15) * NG + lg * 8;

    __syncthreads();

    for (int it = 0; it < ITERS; ++it) {
        const int eb = bb + it * 128 + wid * 16;
        const int erow = eb + lg * 4;

        // ---- indices + r first (feed the hoisted gather) ----
        float rv[4]; int jv[4], iv[4];
        #pragma unroll
        for (int r = 0; r < 4; ++r) {
            rv[r] = r_ij[erow + r];
            jv[r] = ind_j[erow + r];
            iv[r] = ind_i[erow + r];
        }

        // ---- A fragments: global -> registers ----
        float2 q[8];
        #pragma unroll
        for (int p = 0; p < 4; ++p) q[p] = *(const float2*)(aptr + 2 * p);
        #pragma unroll
        for (int p = 0; p < 4; ++p) {
            float2 v = {0.f, 0.f};
            if (lg * 8 + 2 * p <= 16) v = *(const float2*)(aptr + 32 + 2 * p);
            q[4 + p] = v;
        }
        aptr += (size_t)128 * NG;

        // ---- hoisted h-gather: issued here, consumed after GEMM2 ----
        float hv[4][8];
        #pragma unroll
        for (int r = 0; r < 4; ++r) {
            const float* hrow = h + (size_t)jv[r] * NF + l15;
            #pragma unroll
            for (int t = 0; t < 8; ++t) hv[r][t] = hrow[t * 16];
        }

        f16x8 a1[2];
        #pragma unroll
        for (int ks = 0; ks < 2; ++ks) {
            #pragma unroll
            for (int p = 0; p < 4; ++p) {
                f16x2 hvv = __builtin_bit_cast(f16x2,
                    __builtin_amdgcn_cvt_pkrtz(q[ks * 4 + p].x, q[ks * 4 + p].y));
                a1[ks][2 * p]     = hvv[0];
                a1[ks][2 * p + 1] = hvv[1];
            }
        }

        // ---- GEMM1 ----
        f32x4 acc1[8];
        #pragma unroll
        for (int t = 0; t < 8; ++t) acc1[t] = (f32x4){0.f, 0.f, 0.f, 0.f};
        #pragma unroll
        for (int t = 0; t < 8; ++t) {
            f16x8 b0 = *(const f16x8*)(lds + b1b0 + t * 2048);
            f16x8 b1 = *(const f16x8*)(lds + b1b1 + t * 2048);
            acc1[t] = __builtin_amdgcn_mfma_f32_16x16x32_f16(a1[0], b0, acc1[t], 0, 0, 0);
            acc1[t] = __builtin_amdgcn_mfma_f32_16x16x32_f16(a1[1], b1, acc1[t], 0, 0, 0);
        }

        // ---- epilogue1: ssp -> f16 -> per-wave W1OUT ----
        #pragma unroll
        for (int t = 0; t < 8; ++t) {
            #pragma unroll
            for (int r = 0; r < 4; ++r) {
                unsigned short bits = f2h_bits(sspf_fast(acc1[t][r] + b1r[t]));
                int slotx = (2 * (t & 3) + h3) ^ (rw4 + r);
                *(unsigned short*)(lds + ep1base + r * 256 + ((t >> 2) << 7) + (slotx << 4)) = bits;
            }
        }

        // ---- GEMM2 ----
        f32x4 acc2[8];
        #pragma unroll
        for (int t = 0; t < 8; ++t) acc2[t] = (f32x4){0.f, 0.f, 0.f, 0.f};
        f16x8 a2[4];
        #pragma unroll
        for (int ks = 0; ks < 4; ++ks) {
            int addr = ((ks & 1) ? a2b1 : a2b0) + (ks >> 1) * 128;
            a2[ks] = *(const f16x8*)(lds + addr);
        }
        #pragma unroll
        for (int t = 0; t < 8; ++t) {
            #pragma unroll
            for (int ks = 0; ks < 4; ++ks) {
                int addr = ((ks & 1) ? b2b1 : b2b0) + (ks >> 1) * 128 + t * 4096;
                f16x8 b = *(const f16x8*)(lds + addr);
                acc2[t] = __builtin_amdgcn_mfma_f32_16x16x32_f16(a2[ks], b, acc2[t], 0, 0, 0);
            }
        }

        // ---- epilogue2: ssp*cutoff, multiply pre-gathered h, scatter-add ----
        #pragma unroll
        for (int r = 0; r < 4; ++r) {
            float c = 0.5f * (__cosf(rv[r] * PI_OVER_CUT) + 1.0f);
            c = (rv[r] < CUTOFF_F) ? c : 0.0f;
            float* grow = agg + (size_t)iv[r] * NF + l15;
            #pragma unroll
            for (int t = 0; t < 8; ++t) {
                float w2 = sspf_fast(acc2[t][r] + b2r[t]) * c;
                atomicAdd(grow + t * 16, hv[r][t] * w2);
            }
        }
    }
}

extern "C" void kernel_launch(void* const* d_in, const int* in_sizes, int n_in,
                              void* d_out, int out_size, void* d_ws, size_t ws_size,
                              hipStream_t stream) {
    const float* x     = (const float*)d_in[0];
    const float* r_ij  = (const float*)d_in[1];
    const float* f_ij  = (const float*)d_in[2];
    const int*   ind_i = (const int*)d_in[3];
    const int*   ind_j = (const int*)d_in[4];
    const float* Wf1   = (const float*)d_in[5];
    const float* bf1   = (const float*)d_in[6];
    const float* Wf2   = (const float*)d_in[7];
    const float* bf2   = (const float*)d_in[8];
    const float* Win   = (const float*)d_in[9];
    const float* Wout  = (const float*)d_in[10];
    const float* bout  = (const float*)d_in[11];
    float* out = (float*)d_out;

    float*  agg  = (float*)d_ws;
    float*  h    = agg + (size_t)N_ATOMS * NF;
    half_t* w1t  = (half_t*)(h + (size_t)N_ATOMS * NF);
    half_t* w2t  = w1t + 128 * 64;

    (void)hipMemsetAsync(agg, 0, (size_t)N_ATOMS * NF * sizeof(float), stream);

    preconv_kernel<<<96, 256, 0, stream>>>(Wf1, Wf2, w1t, w2t);

    const int gemm_blocks = (N_ATOMS + 31) / 32;
    gemm128_kernel<false><<<gemm_blocks, 256, 0, stream>>>(x, Win, nullptr, h, N_ATOMS);

    edge_kernel<<<N_EDGES / EPB, 512, 0, stream>>>(f_ij, r_ij, ind_i, ind_j,
                                                   w1t, w2t, bf1, bf2, h, agg);

    gemm128_kernel<true><<<gemm_blocks, 256, 0, stream>>>(agg, Wout, bout, out, N_ATOMS);
}